// Round 6
// baseline (2933.663 us; speedup 1.0000x reference)
//
#include <hip/hip_runtime.h>

#define B_ 64
#define T_ 512
#define E_ 512
#define H_ 1024
#define C_ 20
#define NBLK 64
#define RING 16
#define BH (B_ * H_)

typedef __attribute__((ext_vector_type(8))) __bf16 bf16x8;
typedef __attribute__((ext_vector_type(4))) float f32x4;
typedef __attribute__((ext_vector_type(16))) float f32x16;
typedef unsigned long long u64;

__device__ __forceinline__ short f2bf(float x){
  unsigned u = __float_as_uint(x);
  unsigned r = (u + 0x7fffu + ((u >> 16) & 1u)) >> 16;   // RNE
  return (short)r;
}
__device__ __forceinline__ float bf2f(short s){
  return __uint_as_float(((unsigned)(unsigned short)s) << 16);
}

// Relaxed agent-scope ops: single coherent-point (IC) instructions; no
// buffer_inv / buffer_wbl2 anywhere in the persistent loop.
__device__ __forceinline__ u64 ld_agent_u64(const u64* p){
  return __hip_atomic_load(p, __ATOMIC_RELAXED, __HIP_MEMORY_SCOPE_AGENT);
}
__device__ __forceinline__ void st_agent_u64(u64* p, u64 v){
  __hip_atomic_store(p, v, __ATOMIC_RELAXED, __HIP_MEMORY_SCOPE_AGENT);
}

// ---------------------------------------------------------------------------
// Prep: W -> hi/lo bf16 splits, x -> bf16, init h-ring (slot0 = h0 = zeros,
// slots 1..15 = 0xFFFF sentinel). Ring MUST be re-inited every launch (ws is
// not re-poisoned between graph replays).
// ---------------------------------------------------------------------------
__global__ void prep_kernel(const float* __restrict__ x,
                            const float* __restrict__ wih,
                            const float* __restrict__ whh,
                            short* __restrict__ whhh, short* __restrict__ whhl,
                            short* __restrict__ wihh, short* __restrict__ wihl,
                            short* __restrict__ hring,
                            short* __restrict__ xb)
{
  const long NH = (long)H_ * H_;
  const long NI = (long)H_ * E_;
  const long NR = (long)RING * BH;
  const long NX = xb ? (long)B_ * T_ * E_ : 0;
  const long TOT = NH + NI + NR + NX;
  long i = (long)blockIdx.x * blockDim.x + threadIdx.x;
  const long stride = (long)gridDim.x * blockDim.x;
  for (; i < TOT; i += stride){
    if (i < NH){
      float v = whh[i]; short hi = f2bf(v);
      whhh[i] = hi; whhl[i] = f2bf(v - bf2f(hi));
    } else if (i < NH + NI){
      long j = i - NH; float v = wih[j]; short hi = f2bf(v);
      wihh[j] = hi; wihl[j] = f2bf(v - bf2f(hi));
    } else if (i < NH + NI + NR){
      long j = i - NH - NI;
      hring[j] = (j < BH) ? (short)0 : (short)0xFFFF;   // h0 zeros, rest sentinel
    } else {
      long j = i - NH - NI - NR;
      xb[j] = f2bf(x[j]);
    }
  }
}

// ---------------------------------------------------------------------------
// Persistent scan, v2: 64 blocks x 512 threads. Block = (bg in {0,1}) x
// (cg in 0..31): output tile 32 batch x 32 cols via mfma_f32_32x32x16_bf16,
// K=1024 split over 8 waves (128 each). Weights pinned in regs (hi+lo bf16).
//
// Why 64 fat blocks: coherent-point h-read traffic = 128KB x (H/tileN) per
// step. tileN 16->32 halves it (8MB -> 4MB/step); fan-in per consumer 64->32.
//
// Protocol (unchanged from R4/R5): sentinel-validated data polling on a
// 16-slot h ring, 8B single-copy-atomic granules, re-sentinel slot t+8
// (safety window proven by the poll's happens-before), relaxed agent ops
// only. New: arrival-order MFMA fusion — each 16-K chunk's two MFMAs issue
// the moment that chunk validates, so the matrix work rides inside the
// arrival straggle instead of after it.
// ---------------------------------------------------------------------------
__global__ __launch_bounds__(512, 2) void rnn_scan(
    const float* __restrict__ x, const short* __restrict__ xb,
    const short* __restrict__ wihh, const short* __restrict__ wihl,
    const short* __restrict__ whhh, const short* __restrict__ whhl,
    const float* __restrict__ bih, const float* __restrict__ bhh,
    short* __restrict__ hring, float* __restrict__ hT)
{
  const int tid  = threadIdx.x;
  const int lane = tid & 63;
  const int wv   = tid >> 6;          // wave 0..7 -> K slice of 128
  const int bg   = blockIdx.x & 1;    // batch group (32 rows)
  const int cg   = blockIdx.x >> 1;   // col group (32 cols)
  const int l31  = lane & 31;
  const int khi  = lane >> 5;         // 0..1: which 8 of the 16-K chunk

  __shared__ float lds2[8 * 1024];    // per-wave partials at true (row,col)

  const int colRow = cg * 32 + l31;   // output col == W row
  const int hrow   = bg * 32 + l31;   // batch row (A-operand row)

  // --- weight fragments, loaded once then pinned ---
  bf16x8 whhHi[8], whhLo[8];
  #pragma unroll
  for (int c = 0; c < 8; c++){
    int k0 = wv * 128 + c * 16 + khi * 8;
    whhHi[c] = *(const bf16x8*)(whhh + (long)colRow * H_ + k0);
    whhLo[c] = *(const bf16x8*)(whhl + (long)colRow * H_ + k0);
  }
  bf16x8 wihHi[4], wihLo[4];
  #pragma unroll
  for (int c = 0; c < 4; c++){
    int e0 = wv * 64 + c * 16 + khi * 8;
    wihHi[c] = *(const bf16x8*)(wihh + (long)colRow * E_ + e0);
    wihLo[c] = *(const bf16x8*)(wihl + (long)colRow * E_ + e0);
  }
  float bias = bih[colRow] + bhh[colRow];
  #pragma unroll
  for (int c = 0; c < 8; c++)
    asm volatile("" : "+v"(whhHi[c]), "+v"(whhLo[c]));
  #pragma unroll
  for (int c = 0; c < 4; c++)
    asm volatile("" : "+v"(wihHi[c]), "+v"(wihLo[c]));
  asm volatile("" : "+v"(bias));

  // consumer h fragment base: row = hrow, k = wv*128 + c*16 + khi*8
  const long haBase = (long)hrow * H_ + wv * 128 + khi * 8;
  // producer granule (threads 0..255): row = tid>>3, cols (tid&7)*4 ..+4
  const int  prow   = tid >> 3;
  const int  pc0    = (tid & 7) * 4;
  const long pubOff = (long)(bg * 32 + prow) * H_ + cg * 32 + pc0;

  auto load_xa = [&](int tn, int c) -> bf16x8 {
    int e0 = wv * 64 + c * 16 + khi * 8;
    if (xb){
      return *(const bf16x8*)(xb + ((long)hrow * T_ + tn) * E_ + e0);
    } else {
      const float* xp = x + ((long)hrow * T_ + tn) * E_ + e0;
      float4 f0 = *(const float4*)xp;
      float4 f1 = *(const float4*)(xp + 4);
      union { short s[8]; bf16x8 v; } u;
      u.s[0]=f2bf(f0.x); u.s[1]=f2bf(f0.y); u.s[2]=f2bf(f0.z); u.s[3]=f2bf(f0.w);
      u.s[4]=f2bf(f1.x); u.s[5]=f2bf(f1.y); u.s[6]=f2bf(f1.z); u.s[7]=f2bf(f1.w);
      return u.v;
    }
  };

  // x pipeline: cur = x(t), nxt = x(t+1); refill issued a full step early.
  bf16x8 xa_cur[4], xa_nxt[4];
  #pragma unroll
  for (int c = 0; c < 4; c++) xa_cur[c] = load_xa(0, c);
  #pragma unroll
  for (int c = 0; c < 4; c++) xa_nxt[c] = load_xa(1, c);

  for (int t = 0; t < T_; ++t){
    const short* hb = hring + (long)(t & (RING - 1)) * BH + haBase;

    // ---- poll round 0: issue all 8 chunk loads (2 x 8B each) ----
    u64 q0[8], q1[8];
    #pragma unroll
    for (int c = 0; c < 8; c++){
      q0[c] = ld_agent_u64((const u64*)(hb + c * 16));
      q1[c] = ld_agent_u64((const u64*)(hb + c * 16) + 1);
    }

    // ---- x-projection for step t from regs staged 2 steps ago (flight
    //      of the poll loads is hidden under these 8 MFMAs) ----
    float b0 = (wv == 0) ? bias : 0.f;
    f32x16 accH, accL;
    #pragma unroll
    for (int i = 0; i < 16; i++){ accH[i] = b0; accL[i] = 0.f; }
    #pragma unroll
    for (int c = 0; c < 4; c++){
      accH = __builtin_amdgcn_mfma_f32_32x32x16_bf16(xa_cur[c], wihHi[c], accH, 0, 0, 0);
      accL = __builtin_amdgcn_mfma_f32_32x32x16_bf16(xa_cur[c], wihLo[c], accL, 0, 0, 0);
    }

    // ---- validate + arrival-order fused recurrent MFMAs ----
    unsigned need = 0xFFu;
    while (true){
      #pragma unroll
      for (int c = 0; c < 8; c++){
        if (need & (1u << c)){
          bool bad = (((unsigned)q0[c] & 0xFFFFu) == 0xFFFFu) ||
                     (((unsigned)q1[c] & 0xFFFFu) == 0xFFFFu);
          if (!__any(bad)){
            union { u64 q[2]; bf16x8 v; } u;
            u.q[0] = q0[c]; u.q[1] = q1[c];
            accH = __builtin_amdgcn_mfma_f32_32x32x16_bf16(u.v, whhHi[c], accH, 0, 0, 0);
            accL = __builtin_amdgcn_mfma_f32_32x32x16_bf16(u.v, whhLo[c], accL, 0, 0, 0);
            need &= ~(1u << c);
          }
        }
      }
      if (!need) break;
      __builtin_amdgcn_s_sleep(1);      // back off: cut IC poll-storm contention
      #pragma unroll
      for (int c = 0; c < 8; c++){
        if (need & (1u << c)){
          q0[c] = ld_agent_u64((const u64*)(hb + c * 16));
          q1[c] = ld_agent_u64((const u64*)(hb + c * 16) + 1);
        }
      }
    }

    // ---- scatter partials to true (row,col) in lds2[wv]; one lgkm barrier.
    //      C layout (32x32): col = lane&31, row = (r&3) + 8*(r>>2) + 4*khi.
    //      No double-buffer needed: next-step writes are gated by poll t+1,
    //      which requires this step's publishes (data-dependent on reads).
    {
      float* o = lds2 + wv * 1024;
      #pragma unroll
      for (int r = 0; r < 16; r++){
        int row = (r & 3) + 8 * (r >> 2) + 4 * khi;
        o[row * 32 + l31] = accH[r] + accL[r];
      }
    }
    asm volatile("s_waitcnt lgkmcnt(0)\n\ts_barrier" ::: "memory");

    // ---- threads 0..255: 8-way sum, tanh, publish granule ----
    if (tid < 256){
      f32x4 s = *(const f32x4*)&lds2[prow * 32 + pc0];
      #pragma unroll
      for (int p = 1; p < 8; p++)
        s += *(const f32x4*)&lds2[p * 1024 + prow * 32 + pc0];
      float hv[4];
      #pragma unroll
      for (int j = 0; j < 4; j++){
        float a  = fabsf(s[j]);
        float ex = __expf(-2.f * a);
        float r  = (1.f - ex) / (1.f + ex);
        hv[j] = copysignf(r, s[j]);
      }
      if (t < T_ - 1){
        u64 pk =  (u64)(unsigned short)f2bf(hv[0])
               | ((u64)(unsigned short)f2bf(hv[1]) << 16)
               | ((u64)(unsigned short)f2bf(hv[2]) << 32)
               | ((u64)(unsigned short)f2bf(hv[3]) << 48);
        st_agent_u64((u64*)(hring + (long)((t + 1) & (RING - 1)) * BH + pubOff), pk);
        // re-sentinel slot t+8 (holds h[t-8]; all same-bg reads of it are
        // provably complete once our poll of h[t] succeeded). 6 intervening
        // poll-retirements order this commit before our h[t+8] publish.
        if (t + 8 < T_)
          st_agent_u64((u64*)(hring + (long)((t + 8) & (RING - 1)) * BH + pubOff),
                       0xFFFFFFFFFFFFFFFFull);
      } else {
        *(float4*)(hT + pubOff) = make_float4(hv[0], hv[1], hv[2], hv[3]);
      }
    }
    if (t == T_ - 1) break;

    // ---- rotate x pipeline; issue x(t+2) (a full step of latency slack) ----
    #pragma unroll
    for (int c = 0; c < 4; c++) xa_cur[c] = xa_nxt[c];
    if (t + 2 < T_){
      #pragma unroll
      for (int c = 0; c < 4; c++) xa_nxt[c] = load_xa(t + 2, c);
    }
  }
}

// ---------------------------------------------------------------------------
// Head: y1 = relu(hT @ fc1_w^T + b1);  out = y1 @ fc2_w^T + b2   (all fp32)
// ---------------------------------------------------------------------------
__global__ void fc1_kernel(const float* __restrict__ hT, const float* __restrict__ w1,
                           const float* __restrict__ b1, float* __restrict__ y1)
{
  int o = blockIdx.x * 256 + threadIdx.x;     // 0..65535
  int b = o >> 10, j = o & 1023;
  const float4* hp = (const float4*)(hT + (long)b * H_);
  const float4* wp = (const float4*)(w1 + (long)j * H_);
  float s = 0.f;
  #pragma unroll 4
  for (int k = 0; k < H_ / 4; k++){
    float4 hv = hp[k], wv = wp[k];
    s += hv.x * wv.x + hv.y * wv.y + hv.z * wv.z + hv.w * wv.w;
  }
  s += b1[j];
  y1[o] = s > 0.f ? s : 0.f;
}

__global__ void fc2_kernel(const float* __restrict__ y1, const float* __restrict__ w2,
                           const float* __restrict__ b2, float* __restrict__ out)
{
  __shared__ float ybuf[H_];
  int b = blockIdx.x;
  for (int k = threadIdx.x; k < H_; k += 256) ybuf[k] = y1[(long)b * H_ + k];
  __syncthreads();
  if (threadIdx.x < C_){
    const float* wp = w2 + (long)threadIdx.x * H_;
    float s = 0.f;
    for (int k = 0; k < H_; k++) s += ybuf[k] * wp[k];
    out[b * C_ + threadIdx.x] = s + b2[threadIdx.x];
  }
}

// ---------------------------------------------------------------------------
extern "C" void kernel_launch(void* const* d_in, const int* in_sizes, int n_in,
                              void* d_out, int out_size, void* d_ws, size_t ws_size,
                              hipStream_t stream)
{
  const float* x   = (const float*)d_in[0];
  const float* wih = (const float*)d_in[1];
  const float* whh = (const float*)d_in[2];
  const float* bih = (const float*)d_in[3];
  const float* bhh = (const float*)d_in[4];
  const float* w1  = (const float*)d_in[5];
  const float* b1  = (const float*)d_in[6];
  const float* w2  = (const float*)d_in[7];
  const float* b2  = (const float*)d_in[8];
  float* out = (float*)d_out;

  char* ws = (char*)d_ws;
  size_t off = 0;
  auto carve = [&](size_t bytes) -> char* {
    char* p = ws + off; off += (bytes + 255) & ~(size_t)255; return p;
  };
  short*  whhh  = (short*)carve((size_t)H_ * H_ * 2);
  short*  whhl  = (short*)carve((size_t)H_ * H_ * 2);
  short*  wihh  = (short*)carve((size_t)H_ * E_ * 2);
  short*  wihl  = (short*)carve((size_t)H_ * E_ * 2);
  short*  hring = (short*)carve((size_t)RING * BH * 2);
  float*  hT    = (float*)carve((size_t)B_ * H_ * 4);
  float*  y1    = (float*)carve((size_t)B_ * H_ * 4);
  size_t xbytes = (size_t)B_ * T_ * E_ * 2;
  short* xb = (off + xbytes <= ws_size) ? (short*)carve(xbytes) : nullptr;

  prep_kernel<<<2048, 256, 0, stream>>>(x, wih, whh, whhh, whhl, wihh, wihl,
                                        hring, xb);
  rnn_scan<<<NBLK, 512, 0, stream>>>(x, xb, wihh, wihl, whhh, whhl,
                                     bih, bhh, hring, hT);
  fc1_kernel<<<256, 256, 0, stream>>>(hT, w1, b1, y1);
  fc2_kernel<<<64, 256, 0, stream>>>(y1, w2, b2, out);
}

// Round 7
// 2507.261 us; speedup vs baseline: 1.1701x; 1.1701x over previous
//
#include <hip/hip_runtime.h>

#define B_ 64
#define T_ 512
#define E_ 512
#define H_ 1024
#define C_ 20
#define RING 16
#define BH (B_ * H_)

typedef __attribute__((ext_vector_type(8))) _Float16 f16x8;
typedef __attribute__((ext_vector_type(4))) float f32x4;
typedef unsigned long long u64;

__device__ __forceinline__ u64 ld_agent_u64(const u64* p){
  return __hip_atomic_load(p, __ATOMIC_RELAXED, __HIP_MEMORY_SCOPE_AGENT);
}
__device__ __forceinline__ void st_agent_u64(u64* p, u64 v){
  __hip_atomic_store(p, v, __ATOMIC_RELAXED, __HIP_MEMORY_SCOPE_AGENT);
}

// ---------------------------------------------------------------------------
// Prep: W_hh/W_ih/x -> fp16, init h-ring (slot0 = h0 = zeros, slots 1..15 =
// 0xFFFF sentinel = fp16 NaN, never produced by tanh). Ring MUST be re-inited
// every launch (ws not re-poisoned between graph replays).
// ---------------------------------------------------------------------------
__global__ void prep_kernel(const float* __restrict__ x,
                            const float* __restrict__ wih,
                            const float* __restrict__ whh,
                            _Float16* __restrict__ whhF,
                            _Float16* __restrict__ wihF,
                            short* __restrict__ hring,
                            _Float16* __restrict__ xb)
{
  const long NH = (long)H_ * H_;
  const long NI = (long)H_ * E_;
  const long NR = (long)RING * BH;
  const long NX = xb ? (long)B_ * T_ * E_ : 0;
  const long TOT = NH + NI + NR + NX;
  long i = (long)blockIdx.x * blockDim.x + threadIdx.x;
  const long stride = (long)gridDim.x * blockDim.x;
  for (; i < TOT; i += stride){
    if (i < NH){
      whhF[i] = (_Float16)whh[i];
    } else if (i < NH + NI){
      long j = i - NH;
      wihF[j] = (_Float16)wih[j];
    } else if (i < NH + NI + NR){
      long j = i - NH - NI;
      hring[j] = (j < BH) ? (short)0 : (short)0xFFFF;
    } else {
      long j = i - NH - NI - NR;
      xb[j] = (_Float16)x[j];
    }
  }
}

// ---------------------------------------------------------------------------
// Persistent scan v3: 256 blocks x 64 threads — ONE WAVE per block, zero
// barriers, zero cross-wave coupling. Wave (bg,cg) owns output tile
// [16 batches x 16 cols] with FULL K=1024 (no K-split): 32 recurrent +
// 16 input-proj mfma_f32_16x16x32_f16 per step. W_hh (128 VGPR) and W_ih
// (64 VGPR) pinned in registers; launch_bounds(64,1) gives the 512-VGPR
// budget (1 wave/SIMD).
//
// Step cycle (the whole point — nothing else in it):
//   poll h granules (sentinel-validated, arrival-order MFMA fusion)
//   -> tanh -> in-wave LDS transpose (lgkm only, same-wave DS is in-order)
//   -> one 8B agent store per lane (publish) [+ re-sentinel slot t+8]
//   -> stage x(t+1) frags.
// Protocol identical to R4: 16-slot ring, 8B single-copy-atomic granules,
// data-as-flag sentinel polling, re-sentinel t+8 (in-order store retirement
// + 7-step slack orders the reset before the eventual h[t+8] publish).
// ---------------------------------------------------------------------------
__global__ __launch_bounds__(64, 1) void rnn_scan(
    const float* __restrict__ x, const _Float16* __restrict__ xb,
    const _Float16* __restrict__ wihF, const _Float16* __restrict__ whhF,
    const float* __restrict__ bih, const float* __restrict__ bhh,
    _Float16* __restrict__ hring, float* __restrict__ hT)
{
  const int lane = threadIdx.x;       // 0..63 (one wave)
  const int bg   = blockIdx.x >> 6;   // batch group 0..3
  const int cg   = blockIdx.x & 63;   // col group 0..63
  const int r16  = lane & 15;
  const int c4   = lane >> 4;         // 0..3

  __shared__ float tile[16][20];      // padded 16x16 f32 transpose buffer

  const int colRow = cg * 16 + r16;   // output col == W row (B-frag)
  const int hrow   = bg * 16 + r16;   // batch row (A-frag)

  // --- pinned weight fragments: B-frag lane holds W[col=lane&15][k0+(lane>>4)*8+i] ---
  f16x8 wh[32];
  #pragma unroll
  for (int c = 0; c < 32; c++)
    wh[c] = *(const f16x8*)(whhF + (long)colRow * H_ + c * 32 + c4 * 8);
  f16x8 wi[16];
  #pragma unroll
  for (int c = 0; c < 16; c++)
    wi[c] = *(const f16x8*)(wihF + (long)colRow * E_ + c * 32 + c4 * 8);
  float bias = bih[colRow] + bhh[colRow];
  #pragma unroll
  for (int c = 0; c < 32; c++) asm volatile("" : "+v"(wh[c]));
  #pragma unroll
  for (int c = 0; c < 16; c++) asm volatile("" : "+v"(wi[c]));
  asm volatile("" : "+v"(bias));

  const long haOff  = (long)hrow * H_ + c4 * 8;            // + c*32 + slot*BH
  const long pubOff = (long)hrow * H_ + cg * 16 + c4 * 4;  // 8B granule (row, col4)

  auto load_xa = [&](int tn, int c) -> f16x8 {
    if (xb)
      return *(const f16x8*)(xb + ((long)hrow * T_ + tn) * E_ + c * 32 + c4 * 8);
    const float* xp = x + ((long)hrow * T_ + tn) * E_ + c * 32 + c4 * 8;
    f16x8 v;
    #pragma unroll
    for (int j = 0; j < 8; j++) v[j] = (_Float16)xp[j];
    return v;
  };

  // stage x(0)
  f16x8 xa[16];
  #pragma unroll
  for (int c = 0; c < 16; c++) xa[c] = load_xa(0, c);

  for (int t = 0; t < T_; ++t){
    // ---- A) input projection for step t (regs staged last step) ----
    f32x4 accA = { bias, bias, bias, bias };
    f32x4 accB = { 0.f, 0.f, 0.f, 0.f };
    #pragma unroll
    for (int c = 0; c < 16; c += 2){
      accA = __builtin_amdgcn_mfma_f32_16x16x32_f16(xa[c],     wi[c],     accA, 0, 0, 0);
      accB = __builtin_amdgcn_mfma_f32_16x16x32_f16(xa[c + 1], wi[c + 1], accB, 0, 0, 0);
    }

    // ---- B) poll h + arrival-order fused recurrent MFMAs ----
    const _Float16* hb = hring + (long)(t & (RING - 1)) * BH + haOff;
    u64 q0[32], q1[32];
    #pragma unroll
    for (int c = 0; c < 32; c++){
      q0[c] = ld_agent_u64((const u64*)(hb + c * 32));
      q1[c] = ld_agent_u64((const u64*)(hb + c * 32) + 1);
    }
    unsigned need = 0xFFFFFFFFu;
    while (true){
      #pragma unroll
      for (int c = 0; c < 32; c++){
        if (need & (1u << c)){
          bool bad = (((unsigned)q0[c] & 0xFFFFu) == 0xFFFFu) ||
                     (((unsigned)q1[c] & 0xFFFFu) == 0xFFFFu);
          if (!__any(bad)){
            union { u64 q[2]; f16x8 v; } u;
            u.q[0] = q0[c]; u.q[1] = q1[c];
            if (c & 1)
              accB = __builtin_amdgcn_mfma_f32_16x16x32_f16(u.v, wh[c], accB, 0, 0, 0);
            else
              accA = __builtin_amdgcn_mfma_f32_16x16x32_f16(u.v, wh[c], accA, 0, 0, 0);
            need &= ~(1u << c);
          }
        }
      }
      if (!need) break;
      #pragma unroll
      for (int c = 0; c < 32; c++){
        if (need & (1u << c)){
          q0[c] = ld_agent_u64((const u64*)(hb + c * 32));
          q1[c] = ld_agent_u64((const u64*)(hb + c * 32) + 1);
        }
      }
    }
    f32x4 acc = accA + accB;

    // ---- C) tanh ----
    float hv[4];
    #pragma unroll
    for (int j = 0; j < 4; j++){
      float s  = acc[j];
      float a  = fabsf(s);
      float ex = __expf(-2.f * a);
      hv[j] = copysignf((1.f - ex) / (1.f + ex), s);
    }

    // ---- D) in-wave transpose via LDS (C-frag col=r16,row=c4*4+j -> row-granules) ----
    #pragma unroll
    for (int j = 0; j < 4; j++)
      tile[c4 * 4 + j][r16] = hv[j];
    f32x4 o = *(const f32x4*)&tile[r16][c4 * 4];   // compiler inserts lgkmcnt

    if (t < T_ - 1){
      // ---- E) publish one 8B granule + re-sentinel slot t+8 ----
      union { _Float16 h[4]; u64 q; } pu;
      #pragma unroll
      for (int j = 0; j < 4; j++) pu.h[j] = (_Float16)o[j];
      st_agent_u64((u64*)(hring + (long)((t + 1) & (RING - 1)) * BH + pubOff), pu.q);
      if (t + 8 < T_)
        st_agent_u64((u64*)(hring + (long)((t + 8) & (RING - 1)) * BH + pubOff),
                     0xFFFFFFFFFFFFFFFFull);
      // ---- F) stage x(t+1) ----
      #pragma unroll
      for (int c = 0; c < 16; c++) xa[c] = load_xa(t + 1, c);
    } else {
      *(float4*)(hT + pubOff) = make_float4(o[0], o[1], o[2], o[3]);
    }
  }
}

// ---------------------------------------------------------------------------
// Head: y1 = relu(hT @ fc1_w^T + b1);  out = y1 @ fc2_w^T + b2   (all fp32)
// ---------------------------------------------------------------------------
__global__ void fc1_kernel(const float* __restrict__ hT, const float* __restrict__ w1,
                           const float* __restrict__ b1, float* __restrict__ y1)
{
  int o = blockIdx.x * 256 + threadIdx.x;     // 0..65535
  int b = o >> 10, j = o & 1023;
  const float4* hp = (const float4*)(hT + (long)b * H_);
  const float4* wp = (const float4*)(w1 + (long)j * H_);
  float s = 0.f;
  #pragma unroll 4
  for (int k = 0; k < H_ / 4; k++){
    float4 hv = hp[k], wv = wp[k];
    s += hv.x * wv.x + hv.y * wv.y + hv.z * wv.z + hv.w * wv.w;
  }
  s += b1[j];
  y1[o] = s > 0.f ? s : 0.f;
}

__global__ void fc2_kernel(const float* __restrict__ y1, const float* __restrict__ w2,
                           const float* __restrict__ b2, float* __restrict__ out)
{
  __shared__ float ybuf[H_];
  int b = blockIdx.x;
  for (int k = threadIdx.x; k < H_; k += 256) ybuf[k] = y1[(long)b * H_ + k];
  __syncthreads();
  if (threadIdx.x < C_){
    const float* wp = w2 + (long)threadIdx.x * H_;
    float s = 0.f;
    for (int k = 0; k < H_; k++) s += ybuf[k] * wp[k];
    out[b * C_ + threadIdx.x] = s + b2[threadIdx.x];
  }
}

// ---------------------------------------------------------------------------
extern "C" void kernel_launch(void* const* d_in, const int* in_sizes, int n_in,
                              void* d_out, int out_size, void* d_ws, size_t ws_size,
                              hipStream_t stream)
{
  const float* x   = (const float*)d_in[0];
  const float* wih = (const float*)d_in[1];
  const float* whh = (const float*)d_in[2];
  const float* bih = (const float*)d_in[3];
  const float* bhh = (const float*)d_in[4];
  const float* w1  = (const float*)d_in[5];
  const float* b1  = (const float*)d_in[6];
  const float* w2  = (const float*)d_in[7];
  const float* b2  = (const float*)d_in[8];
  float* out = (float*)d_out;

  char* ws = (char*)d_ws;
  size_t off = 0;
  auto carve = [&](size_t bytes) -> char* {
    char* p = ws + off; off += (bytes + 255) & ~(size_t)255; return p;
  };
  _Float16* whhF  = (_Float16*)carve((size_t)H_ * H_ * 2);
  _Float16* wihF  = (_Float16*)carve((size_t)H_ * E_ * 2);
  _Float16* hring = (_Float16*)carve((size_t)RING * BH * 2);
  float*    hT    = (float*)carve((size_t)B_ * H_ * 4);
  float*    y1    = (float*)carve((size_t)B_ * H_ * 4);
  size_t xbytes = (size_t)B_ * T_ * E_ * 2;
  _Float16* xb = (off + xbytes <= ws_size) ? (_Float16*)carve(xbytes) : nullptr;

  prep_kernel<<<2048, 256, 0, stream>>>(x, wih, whh, whhF, wihF,
                                        (short*)hring, xb);
  rnn_scan<<<256, 64, 0, stream>>>(x, xb, wihF, whhF, bih, bhh, hring, hT);
  fc1_kernel<<<256, 256, 0, stream>>>(hT, w1, b1, y1);
  fc2_kernel<<<64, 256, 0, stream>>>(y1, w2, b2, out);
}